// Round 9
// baseline (1764.492 us; speedup 1.0000x reference)
//
#include <hip/hip_runtime.h>

// HierarchicalResidualQuantizer on gfx950 — numpy-fp32-exact decision path.
// N=16384 tokens, D=256, L=8 levels, K=512 codes.
// Outputs (flat fp32 in d_out): q_out[16,256,32,32] @0, indices[16,32,32,8] @4194304,
// loss[16] @4325376, all_probs[16384,8,512] @4325392.  Total 71,434,256 floats.
// Scratch lives in the TAIL of the probs region (overwritten last by k_out2).
//
// R9: per-level fusion. k_lvl<<<512,256>>> does the level's scoring; each block
// release-fences + bumps done[lvl]; the last 128 finishers spin to done==512
// (they are resident; non-workers retire -> no deadlock) and become gsum
// workers: 2 dims each via LDS producer/consumer ping-pong (chain-latency
// bound), 128th worker recomputes G2 (device-coherent atomic g32 reads).
// Phase B/E now read a 32KB LDS-staged z slice (residuals written in-place,
// bit-identical fl32 values). Chain + decision arithmetic unchanged from the
// validated R4-R8 lineage.

typedef _Float16 f16;
typedef _Float16 half8 __attribute__((ext_vector_type(8)));
typedef _Float16 half4v __attribute__((ext_vector_type(4)));
typedef float f32x4 __attribute__((ext_vector_type(4)));

#define LOGK 6.238324625039508f

#define OUT_IDX 4194304
#define OUT_LOSS 4325376
#define OUT_PROBS 4325392

#define SCR_FLOATS 5526800
// scratch offsets in floats
#define SF_ZH 0              // f16[16384*256]
#define SF_ZL 2097152        // f16[16384*256]
#define SF_WH 4194304        // f16[4096*256]
#define SF_WL 4718592        // f16[4096*256]
#define SF_B32 5242880       // float[4096]  fp32 pairwise ||w||^2 (numpy-exact)
#define SF_G32 5246976       // float[256]   fp32 global_sum (numpy-exact bits)
#define SF_G2D 5247232       // double[512]  2*g.w_k for next level (approx path)
#define SF_IDX 5248256       // int[16384*8]
#define SF_IDXL 5379328      // int[8*16384] level-major indices
#define SF_KL 5510400        // float[16384]
#define SF_DONE 5526784      // int[16]: done[8] + done2[8]

__device__ __forceinline__ float np_combine8(const float r[8]) {
    return __fadd_rn(__fadd_rn(__fadd_rn(r[0], r[1]), __fadd_rn(r[2], r[3])),
                     __fadd_rn(__fadd_rn(r[4], r[5]), __fadd_rn(r[6], r[7])));
}

__global__ void k_prep_z(const float* __restrict__ z, f16* __restrict__ zh, f16* __restrict__ zl) {
    int i = (blockIdx.x * 256 + threadIdx.x) * 4;
    float4 v = *(const float4*)(z + i);
    half4v h, l;
    float c0 = v.x, c1 = v.y, c2 = v.z, c3 = v.w;
    f16 h0 = (f16)c0, h1 = (f16)c1, h2 = (f16)c2, h3 = (f16)c3;
    h[0] = h0; h[1] = h1; h[2] = h2; h[3] = h3;
    l[0] = (f16)(c0 - (float)h0); l[1] = (f16)(c1 - (float)h1);
    l[2] = (f16)(c2 - (float)h2); l[3] = (f16)(c3 - (float)h3);
    *(half4v*)(zh + i) = h;
    *(half4v*)(zl + i) = l;
}

// bid<1024: fp16 hi/lo split of scaled codebooks. bid>=1024: numpy-exact b32
// rows (+ misc init on bid==1024).
__global__ void k_prep_wb(const float* __restrict__ w, f16* __restrict__ wh, f16* __restrict__ wl,
                          float* __restrict__ b32, float* __restrict__ g32,
                          double* __restrict__ G2, float* __restrict__ loss_out,
                          int* __restrict__ done) {
    int tid = threadIdx.x;
    if (blockIdx.x < 1024) {
        int row = blockIdx.x * 4 + (tid >> 6);
        int lane = tid & 63;
        int lvl = row >> 9;
        float sc = (float)(1 << (lvl + 4));
        const float* wr = w + row * 256;
        int d0 = lane * 4;
        float4 v = *(const float4*)(wr + d0);
        half4v h, l;
        float s0 = v.x * sc, s1 = v.y * sc, s2 = v.z * sc, s3 = v.w * sc;
        f16 h0 = (f16)s0, h1 = (f16)s1, h2 = (f16)s2, h3 = (f16)s3;
        h[0] = h0; h[1] = h1; h[2] = h2; h[3] = h3;
        l[0] = (f16)(s0 - (float)h0); l[1] = (f16)(s1 - (float)h1);
        l[2] = (f16)(s2 - (float)h2); l[3] = (f16)(s3 - (float)h3);
        *(half4v*)(wh + row * 256 + d0) = h;
        *(half4v*)(wl + row * 256 + d0) = l;
    } else {
        int row = (blockIdx.x - 1024) * 256 + tid;   // 0..4095
        const float* wr = w + row * 256;
        float res[2];
        #pragma unroll
        for (int h = 0; h < 2; ++h) {
            const float* x = wr + h * 128;
            float r[8];
            #pragma unroll
            for (int j = 0; j < 8; ++j) r[j] = __fmul_rn(x[j], x[j]);
            for (int i = 8; i < 128; i += 8)
                #pragma unroll
                for (int j = 0; j < 8; ++j) r[j] = __fadd_rn(r[j], __fmul_rn(x[i + j], x[i + j]));
            res[h] = np_combine8(r);
        }
        b32[row] = __fadd_rn(res[0], res[1]);
        if (blockIdx.x == 1024) {
            g32[tid] = 0.0f;
            G2[tid] = 0.0; G2[tid + 256] = 0.0;
            if (tid < 16) loss_out[tid] = 0.0f;
            if (tid < 16) done[tid] = 0;
        }
    }
}

// Fused per-level kernel: scoring (phase 1) + g-chain/G2 (phase 2, last 128
// finishers). See header comment.
__global__ __launch_bounds__(256) void k_lvl(
        const float* __restrict__ zf, const float* __restrict__ wf,
        const f16* __restrict__ zh, const f16* __restrict__ zl,
        const f16* __restrict__ wh, const f16* __restrict__ wl,
        float* __restrict__ g32, double* __restrict__ G2,
        const float* __restrict__ b32,
        int* __restrict__ idxws, int* __restrict__ idxL,
        float* __restrict__ klacc, int* __restrict__ done, int lvl, int do_gsum) {
    __shared__ union {
        struct {
            float bS[512];
            float g2S[512];
            float gS[256];
            float zS[32 * 260];     // z slice, then residuals (in-place)
            float pb[32][16];
            float aS[32], mgS[32];
            float DmaxW[4][32], DmaxS[32];
            float seW[4][32], sdW[4][32];
            unsigned short cand[32][256];
            int ccnt[32];
            int bidxS[32];
        } p1;
        struct {
            float wcol[512 * 3];    // [code][dim(2), stride 3]
            float vals[2][2][520];  // [buf][dim][token-in-chunk]
        } p2;
    } sh;
    __shared__ float gfS[256];
    __shared__ int svprev;

    const int tid = threadIdx.x;
    const int wave = tid >> 6, lane = tid & 63;
    const int quad = lane >> 4, lr = lane & 15;
    const int tok0 = blockIdx.x * 32;
    const int code0 = wave * 128;

    // stage
    sh.p1.gS[tid] = g32[tid];
    sh.p1.bS[tid] = b32[lvl * 512 + tid];
    sh.p1.bS[tid + 256] = b32[lvl * 512 + tid + 256];
    sh.p1.g2S[tid] = (float)G2[tid];
    sh.p1.g2S[tid + 256] = (float)G2[tid + 256];
    if (tid < 32) sh.p1.ccnt[tid] = 0;
    {   // coalesced z slice -> zS (raw z for now)
        const float4* zsrc = (const float4*)(zf + tok0 * 256);
        #pragma unroll
        for (int i = 0; i < 8; ++i) {
            int fi = tid + i * 256;               // 0..2047 float4
            int t = fi >> 6, j4 = fi & 63;
            *(float4*)(&sh.p1.zS[t * 260 + j4 * 4]) = zsrc[fi];
        }
    }

    // Phase A: MFMA approx (3-term fp16 split, fp32 acc)
    const f16* za = zh + (tok0 + lr) * 256 + quad * 8;
    const f16* zb = zl + (tok0 + lr) * 256 + quad * 8;
    const f16* wa = wh + (lvl * 512 + code0 + lr) * 256 + quad * 8;
    const f16* wb = wl + (lvl * 512 + code0 + lr) * 256 + quad * 8;
    f32x4 acc[2][8];
    #pragma unroll
    for (int mt = 0; mt < 2; ++mt)
        #pragma unroll
        for (int nt = 0; nt < 8; ++nt)
            acc[mt][nt] = (f32x4){0.f, 0.f, 0.f, 0.f};
    for (int k0 = 0; k0 < 256; k0 += 32) {
        half8 ah0 = *(const half8*)(za + k0);
        half8 ah1 = *(const half8*)(za + 16 * 256 + k0);
        half8 al0 = *(const half8*)(zb + k0);
        half8 al1 = *(const half8*)(zb + 16 * 256 + k0);
        half8 bh[8], bl[8];
        #pragma unroll
        for (int nt = 0; nt < 8; ++nt) {
            bh[nt] = *(const half8*)(wa + nt * 16 * 256 + k0);
            bl[nt] = *(const half8*)(wb + nt * 16 * 256 + k0);
        }
        #pragma unroll
        for (int nt = 0; nt < 8; ++nt) {
            acc[0][nt] = __builtin_amdgcn_mfma_f32_16x16x32_f16(ah0, bh[nt], acc[0][nt], 0, 0, 0);
            acc[1][nt] = __builtin_amdgcn_mfma_f32_16x16x32_f16(ah1, bh[nt], acc[1][nt], 0, 0, 0);
            acc[0][nt] = __builtin_amdgcn_mfma_f32_16x16x32_f16(ah0, bl[nt], acc[0][nt], 0, 0, 0);
            acc[1][nt] = __builtin_amdgcn_mfma_f32_16x16x32_f16(ah1, bl[nt], acc[1][nt], 0, 0, 0);
            acc[0][nt] = __builtin_amdgcn_mfma_f32_16x16x32_f16(al0, bh[nt], acc[0][nt], 0, 0, 0);
            acc[1][nt] = __builtin_amdgcn_mfma_f32_16x16x32_f16(al1, bh[nt], acc[1][nt], 0, 0, 0);
        }
    }
    __syncthreads();

    // Phase B: a_n = numpy-pairwise fp32 sum of resid^2; residuals written
    // back into zS in-place (same __fsub_rn bits Phase E needs).
    {
        int t = tid >> 3, s = tid & 7;
        float* zr = &sh.p1.zS[t * 260];
        #pragma unroll
        for (int h = 0; h < 2; ++h) {
            int base = h * 128 + s;
            float xv = __fsub_rn(zr[base], sh.p1.gS[base]);
            zr[base] = xv;
            float r = __fmul_rn(xv, xv);
            for (int i = 1; i < 16; ++i) {
                int o = base + i * 8;
                float x2 = __fsub_rn(zr[o], sh.p1.gS[o]);
                zr[o] = x2;
                r = __fadd_rn(r, __fmul_rn(x2, x2));
            }
            sh.p1.pb[t][h * 8 + s] = r;
        }
    }
    __syncthreads();
    if (tid < 32) {
        float r0[8], r1[8];
        #pragma unroll
        for (int j = 0; j < 8; ++j) { r0[j] = sh.p1.pb[tid][j]; r1[j] = sh.p1.pb[tid][8 + j]; }
        float a = __fadd_rn(np_combine8(r0), np_combine8(r1));
        sh.p1.aS[tid] = a;
        unsigned e = (__float_as_uint(a) >> 23) & 0xffu;
        float ulp = __uint_as_float((e - 23u) << 23);
        sh.p1.mgS[tid] = 2.5f * ulp + 1e-4f * sqrtf(a) / (float)(1 << lvl) + 1e-6f;
    }
    __syncthreads();

    // Phase C: emulated fp32 dist computed once, stored in-place in acc
    const float inv2f = 1.0f / (float)(1 << (lvl + 3));
    float b8[8], g28[8];
    #pragma unroll
    for (int nt = 0; nt < 8; ++nt) {
        b8[nt] = sh.p1.bS[code0 + nt * 16 + lr];
        g28[nt] = sh.p1.g2S[code0 + nt * 16 + lr];
    }
    #pragma unroll
    for (int mt = 0; mt < 2; ++mt) {
        #pragma unroll
        for (int r = 0; r < 4; ++r) {
            int tl = mt * 16 + quad * 4 + r;
            float a = sh.p1.aS[tl];
            float m = -3.4e38f;
            #pragma unroll
            for (int nt = 0; nt < 8; ++nt) {
                float c2 = __fsub_rn(__fmul_rn(acc[mt][nt][r], inv2f), g28[nt]);
                float D = -__fsub_rn(__fadd_rn(a, b8[nt]), c2);
                acc[mt][nt][r] = D;
                m = fmaxf(m, D);
            }
            #pragma unroll
            for (int msk = 1; msk < 16; msk <<= 1) m = fmaxf(m, __shfl_xor(m, msk));
            if (lr == 0) sh.p1.DmaxW[wave][tl] = m;
        }
    }
    __syncthreads();
    if (tid < 32)
        sh.p1.DmaxS[tid] = fmaxf(fmaxf(sh.p1.DmaxW[0][tid], sh.p1.DmaxW[1][tid]),
                                 fmaxf(sh.p1.DmaxW[2][tid], sh.p1.DmaxW[3][tid]));
    __syncthreads();

    // Phase C2: softmax stats + candidate collection
    #pragma unroll
    for (int mt = 0; mt < 2; ++mt) {
        #pragma unroll
        for (int r = 0; r < 4; ++r) {
            int tl = mt * 16 + quad * 4 + r;
            float Dm = sh.p1.DmaxS[tl], mg = sh.p1.mgS[tl];
            float se = 0.f, sd = 0.f;
            #pragma unroll
            for (int nt = 0; nt < 8; ++nt) {
                float D = acc[mt][nt][r];
                float d = Dm - D;
                se += __expf(-d);
                sd += d;
                if (D >= Dm - mg) {
                    int pos = atomicAdd(&sh.p1.ccnt[tl], 1);
                    if (pos < 256) sh.p1.cand[tl][pos] = (unsigned short)(code0 + nt * 16 + lr);
                }
            }
            #pragma unroll
            for (int msk = 1; msk < 16; msk <<= 1) {
                se += __shfl_xor(se, msk);
                sd += __shfl_xor(sd, msk);
            }
            if (lr == 0) { sh.p1.seW[wave][tl] = se; sh.p1.sdW[wave][tl] = sd; }
        }
    }
    __syncthreads();

    if (tid < 32) {
        float se = sh.p1.seW[0][tid] + sh.p1.seW[1][tid] + sh.p1.seW[2][tid] + sh.p1.seW[3][tid];
        float sd = sh.p1.sdW[0][tid] + sh.p1.sdW[1][tid] + sh.p1.sdW[2][tid] + sh.p1.sdW[3][tid];
        float kl = __logf(se) + sd * (1.0f / 512.0f) - LOGK;
        int n = tok0 + tid;
        float prev = (lvl == 0) ? 0.0f : klacc[n];
        klacc[n] = prev + 0.1f * kl;
    }

    // Phase E: exact numpy-fp32 dist for candidates (residuals from LDS,
    // sequential-FMA c — bit-identical to the validated path)
    {
        int t = tid >> 3, s = tid & 7;
        const float* rr = &sh.p1.zS[t * 260];
        int cnt = sh.p1.ccnt[t]; if (cnt > 256) cnt = 256;
        float aT = sh.p1.aS[t];
        float bD = -3.4e38f; int bI = 0x7fffffff;
        for (int ci = s; ci < cnt; ci += 8) {
            int code = sh.p1.cand[t][ci];
            const float* wr = wf + (lvl * 512 + code) * 256;
            float c = 0.f;
            #pragma unroll 8
            for (int j = 0; j < 256; ++j)
                c = fmaf(rr[j], wr[j], c);
            float D = -__fsub_rn(__fadd_rn(aT, sh.p1.bS[code]), __fadd_rn(c, c));
            if (D > bD || (D == bD && code < bI)) { bD = D; bI = code; }
        }
        #pragma unroll
        for (int msk = 1; msk < 8; msk <<= 1) {
            float oD = __shfl_xor(bD, msk);
            int oI = __shfl_xor(bI, msk);
            if (oD > bD || (oD == bD && oI < bI)) { bD = oD; bI = oI; }
        }
        if (s == 0) sh.p1.bidxS[t] = bI;
    }
    __syncthreads();
    if (tid < 32) {
        int gi = sh.p1.bidxS[tid];
        int n = tok0 + tid;
        idxws[n * 8 + lvl] = gi;
        idxL[lvl * 16384 + n] = gi;
    }

    if (!do_gsum) return;

    // ---- phase 1 -> phase 2 handoff ----
    __syncthreads();
    __threadfence();                       // release our idxL/klacc stores
    if (tid == 0) svprev = atomicAdd(&done[lvl], 1);
    __syncthreads();
    int prev = svprev;
    if (prev < 384) return;                // not a gsum worker
    const int wid = prev - 384;            // 0..127, dims 2*wid..2*wid+1
    if (tid == 0) {
        while (__hip_atomic_load(&done[lvl], __ATOMIC_ACQUIRE, __HIP_MEMORY_SCOPE_AGENT) < 512)
            __builtin_amdgcn_s_sleep(2);
    }
    __syncthreads();
    __threadfence();                       // acquire: idxL from all blocks

    // ---- phase 2: numpy-exact g chain for dims d0, d0+1 ----
    const int d0 = wid * 2;
    {   // stage 512x2 column slice, stride 3 (bank spread)
        const float* wbase = wf + lvl * 131072 + d0;
        for (int i = tid; i < 1024; i += 256)
            sh.p2.wcol[(i >> 1) * 3 + (i & 1)] = wbase[(i >> 1) * 256 + (i & 1)];
    }
    const int* __restrict__ codes = idxL + lvl * 16384;
    const bool producer = (tid < 192);
    const int cl = tid - 254;              // consumer lanes: tid 254,255
    __syncthreads();
    if (producer) {
        for (int k = tid; k < 512; k += 192) {
            int c = codes[k] * 3;
            float v0 = sh.p2.wcol[c], v1 = sh.p2.wcol[c + 1];
            sh.p2.vals[0][0][k] = v0;
            sh.p2.vals[0][1][k] = v1;
        }
    }
    __syncthreads();
    float accg = 0.f;
    for (int ch = 0; ch < 32; ++ch) {
        const int cb = ch & 1, nb = cb ^ 1;
        if (producer) {
            if (ch < 31) {
                int base = (ch + 1) << 9;
                for (int k = tid; k < 512; k += 192) {
                    int c = codes[base + k] * 3;
                    float v0 = sh.p2.wcol[c], v1 = sh.p2.wcol[c + 1];
                    sh.p2.vals[nb][0][k] = v0;
                    sh.p2.vals[nb][1][k] = v1;
                }
            }
        } else if (cl >= 0) {
            const float4* vp = (const float4*)(&sh.p2.vals[cb][cl][0]);  // 128 float4
            float4 A[16], B[16];
            #pragma unroll
            for (int j = 0; j < 16; ++j) A[j] = vp[j];
            #pragma unroll
            for (int s = 0; s < 8; ++s) {
                if ((s & 1) == 0) {
                    if (s < 7) {
                        #pragma unroll
                        for (int j = 0; j < 16; ++j) B[j] = vp[(s + 1) * 16 + j];
                    }
                    #pragma unroll
                    for (int j = 0; j < 16; ++j) {
                        accg = __fadd_rn(accg, A[j].x);
                        accg = __fadd_rn(accg, A[j].y);
                        accg = __fadd_rn(accg, A[j].z);
                        accg = __fadd_rn(accg, A[j].w);
                    }
                } else {
                    if (s < 7) {
                        #pragma unroll
                        for (int j = 0; j < 16; ++j) A[j] = vp[(s + 1) * 16 + j];
                    }
                    #pragma unroll
                    for (int j = 0; j < 16; ++j) {
                        accg = __fadd_rn(accg, B[j].x);
                        accg = __fadd_rn(accg, B[j].y);
                        accg = __fadd_rn(accg, B[j].z);
                        accg = __fadd_rn(accg, B[j].w);
                    }
                }
            }
        }
        __syncthreads();
    }
    if (cl >= 0) {
        int d = d0 + cl;
        g32[d] = __fadd_rn(g32[d], accg);
    }
    __threadfence();                       // release g32
    __syncthreads();
    if (tid == 0) svprev = atomicAdd(&done[8 + lvl], 1);
    __syncthreads();
    if (svprev != 127) return;

    // ---- last worker: G2[k] = 2 * g . W_{l+1}[k,:] (fp64) ----
    __threadfence();
    gfS[tid] = atomicAdd(&g32[tid], 0.0f); // device-coherent read
    __syncthreads();
    const float* wn = wf + (lvl + 1) * 131072;
    for (int k = tid; k < 512; k += 256) {
        const float* wr = wn + k * 256;
        double s = 0.0;
        for (int j = 0; j < 256; ++j) s = fma((double)gfS[j], (double)wr[j], s);
        G2[k] = 2.0 * s;
    }
}

// Epilogue 1: q_out (transposed), indices (as float), per-image loss.
__global__ __launch_bounds__(256) void k_out1(const float* __restrict__ w,
        const float* __restrict__ b32, const int* __restrict__ idxws,
        const float* __restrict__ klacc, float* __restrict__ out) {
    __shared__ int lidx[64][8];
    int tid = threadIdx.x;
    int tok0 = blockIdx.x * 64;
    int b = tok0 >> 10, hw0 = tok0 & 1023;

    for (int s = tid; s < 512; s += 256) {
        int v = idxws[tok0 * 8 + s];
        lidx[s >> 3][s & 7] = v;
        out[OUT_IDX + tok0 * 8 + s] = (float)v;
    }
    __syncthreads();

    {
        int j = tid & 63, q = tid >> 6;
        int id[8];
        #pragma unroll
        for (int l = 0; l < 8; ++l) id[l] = lidx[j][l];
        for (int dd = 0; dd < 64; ++dd) {
            int d = q * 64 + dd;
            float s = 0.f;
            #pragma unroll
            for (int l = 0; l < 8; ++l) s += w[l * 131072 + id[l] * 256 + d];
            out[b * 262144 + d * 1024 + hw0 + j] = s;
        }
    }

    if (tid < 64) {
        int n = tok0 + tid;
        float lv = klacc[n];
        float nl = 0.f;
        #pragma unroll
        for (int jj = 0; jj < 7; ++jj) {
            float up = sqrtf(b32[jj * 512 + lidx[tid][jj]]);
            float lo = sqrtf(b32[(jj + 1) * 512 + lidx[tid][jj + 1]]);
            float ratio = 4.0f * (lo / up);
            float m = fmaxf(ratio, 1.0f) - 1.0f;
            nl += m * m;
        }
        lv += nl * (1.0f / 7.0f) * 0.1f;
        #pragma unroll
        for (int msk = 1; msk < 64; msk <<= 1) lv += __shfl_xor(lv, msk);
        if (tid == 0) atomicAdd(out + OUT_LOSS + b, lv * (1.0f / 1024.0f));
    }
}

// Epilogue 2: fill the ENTIRE probs region (one-hot), overwriting scratch tail.
// Reads indices from OUT_IDX (written by k_out1) to avoid racing the tail.
__global__ __launch_bounds__(256) void k_out2(float* __restrict__ out) {
    __shared__ int lidx[16][8];
    int tid = threadIdx.x;
    int tok0 = blockIdx.x * 16;
    if (tid < 128) {
        int v = (int)out[OUT_IDX + tok0 * 8 + tid];
        lidx[tid >> 3][tid & 7] = v;
    }
    __syncthreads();
    float4* pb = (float4*)(out + OUT_PROBS) + (size_t)tok0 * 1024;
    for (int it = 0; it < 64; ++it) {
        int i = it * 256 + tid;
        int nl_ = i >> 10, l = (i >> 7) & 7, kg = i & 127;
        int rel = lidx[nl_][l] - kg * 4;
        float4 v;
        v.x = (rel == 0) ? 1.0f : 0.0f;
        v.y = (rel == 1) ? 1.0f : 0.0f;
        v.z = (rel == 2) ? 1.0f : 0.0f;
        v.w = (rel == 3) ? 1.0f : 0.0f;
        pb[i] = v;
    }
}

extern "C" void kernel_launch(void* const* d_in, const int* in_sizes, int n_in,
                              void* d_out, int out_size, void* d_ws, size_t ws_size,
                              hipStream_t stream) {
    const float* z = (const float*)d_in[0];
    const float* w = (const float*)d_in[1];
    float* out = (float*)d_out;

    float* sb = out + (out_size - SCR_FLOATS);
    f16* zh = (f16*)(sb + SF_ZH);
    f16* zl = (f16*)(sb + SF_ZL);
    f16* wh = (f16*)(sb + SF_WH);
    f16* wl = (f16*)(sb + SF_WL);
    float* b32 = (float*)(sb + SF_B32);
    float* g32 = (float*)(sb + SF_G32);
    double* G2 = (double*)(sb + SF_G2D);
    int* idxws = (int*)(sb + SF_IDX);
    int* idxL = (int*)(sb + SF_IDXL);
    float* klacc = (float*)(sb + SF_KL);
    int* done = (int*)(sb + SF_DONE);

    k_prep_z<<<4096, 256, 0, stream>>>(z, zh, zl);
    k_prep_wb<<<1040, 256, 0, stream>>>(w, wh, wl, b32, g32, G2, out + OUT_LOSS, done);
    for (int l = 0; l < 8; ++l)
        k_lvl<<<512, 256, 0, stream>>>(z, w, zh, zl, wh, wl, g32, G2, b32,
                                       idxws, idxL, klacc, done, l, (l < 7) ? 1 : 0);
    k_out1<<<256, 256, 0, stream>>>(w, b32, idxws, klacc, out);
    k_out2<<<1024, 256, 0, stream>>>(out);
}